// Round 1
// baseline (2210.415 us; speedup 1.0000x reference)
//
#include <hip/hip_runtime.h>
#include <hip/hip_bf16.h>

#define T_NODES 256000
#define B_BATCH 512
#define NPB     500
#define DIM     128
#define VOCAB   50000
#define MAXD    40

// ---------------- zero small meta ----------------
__global__ void zero_k(int* counts) {
    if (threadIdx.x <= MAXD) counts[threadIdx.x] = 0;
}

// ---------------- E = emb @ Wc + bc (f32, LDS-tiled) ----------------
// grid: VOCAB/8 blocks, 256 threads. Each block: 8 vocab rows.
__global__ __launch_bounds__(256) void gemm_E(const float* __restrict__ emb,
                                              const float* __restrict__ Wc,
                                              const float* __restrict__ bc,
                                              float* __restrict__ E) {
    __shared__ float sW[DIM * DIM];     // 64 KB
    __shared__ float sE[8][DIM];        // 4 KB
    // load Wc (16384 floats = 4096 float4)
    for (int i = threadIdx.x; i < DIM * DIM / 4; i += 256)
        ((float4*)sW)[i] = ((const float4*)Wc)[i];
    int rowBase = blockIdx.x * 8;
    // load 8 emb rows (1024 floats = 256 float4)
    ((float4*)&sE[0][0])[threadIdx.x] = ((const float4*)(emb + (long long)rowBase * DIM))[threadIdx.x];
    __syncthreads();

    int r  = threadIdx.x >> 5;          // 0..7
    int j4 = (threadIdx.x & 31) * 4;    // 0..124
    float4 acc = make_float4(0.f, 0.f, 0.f, 0.f);
    #pragma unroll 8
    for (int k = 0; k < DIM; ++k) {
        float e = sE[r][k];
        float4 w = *(float4*)&sW[k * DIM + j4];
        acc.x += e * w.x; acc.y += e * w.y; acc.z += e * w.z; acc.w += e * w.w;
    }
    float4 b4 = *(const float4*)&bc[j4];
    acc.x += b4.x; acc.y += b4.y; acc.z += b4.z; acc.w += b4.w;
    *(float4*)&E[(long long)(rowBase + r) * DIM + j4] = acc;
}

// ---------------- v[n] = E[tokens[n]] ; histogram depths ----------------
// grid: T/8 blocks, 256 threads (8 nodes x 32 j-quads per block)
__global__ __launch_bounds__(256) void gather_init(const int* __restrict__ tokens,
                                                   const int* __restrict__ depth,
                                                   const float* __restrict__ E,
                                                   float* __restrict__ v,
                                                   int* __restrict__ counts) {
    __shared__ int hist[MAXD + 1];
    if (threadIdx.x <= MAXD) hist[threadIdx.x] = 0;
    __syncthreads();

    int n  = blockIdx.x * 8 + (threadIdx.x >> 5);
    int j4 = (threadIdx.x & 31) * 4;
    int tok = tokens[n];
    float4 val = *(const float4*)&E[(long long)tok * DIM + j4];
    *(float4*)&v[(long long)n * DIM + j4] = val;
    if (j4 == 0) atomicAdd(&hist[depth[n]], 1);

    __syncthreads();
    if (threadIdx.x <= MAXD) {
        int h = hist[threadIdx.x];
        if (h > 0) atomicAdd(&counts[threadIdx.x], h);
    }
}

// ---------------- prefix over 41 counts ----------------
__global__ void offsets_k(const int* __restrict__ counts, int* __restrict__ offsets,
                          int* __restrict__ cursor) {
    if (threadIdx.x == 0) {
        int acc = 0;
        for (int d = 0; d <= MAXD; ++d) {
            offsets[d] = acc; cursor[d] = acc; acc += counts[d];
        }
    }
}

// ---------------- scatter node ids into depth buckets ----------------
__global__ __launch_bounds__(256) void scatter_k(const int* __restrict__ depth,
                                                 int* __restrict__ cursor,
                                                 int* __restrict__ list) {
    int n = blockIdx.x * 256 + threadIdx.x;
    if (n < T_NODES) {
        int d = depth[n];
        int pos = atomicAdd(&cursor[d], 1);
        list[pos] = n;
    }
}

// ---------------- one propagation level: v[parent] += v[node] ----------------
// fixed grid (512x256), grid-stride over count[d]*32 (node, j4) tasks
__global__ __launch_bounds__(256) void level_k(int d,
                                               const int* __restrict__ offsets,
                                               const int* __restrict__ counts,
                                               const int* __restrict__ list,
                                               const int* __restrict__ parent,
                                               float* __restrict__ v) {
    int c   = counts[d];
    int off = offsets[d];
    int tasks = c * 32;
    for (int t = blockIdx.x * 256 + threadIdx.x; t < tasks; t += gridDim.x * 256) {
        int idx = t >> 5;
        int j4  = (t & 31) * 4;
        int n = list[off + idx];
        int p = parent[n];
        float4 val = *(const float4*)&v[(long long)n * DIM + j4];
        float* dst = &v[(long long)p * DIM + j4];
        unsafeAtomicAdd(dst + 0, val.x);
        unsafeAtomicAdd(dst + 1, val.y);
        unsafeAtomicAdd(dst + 2, val.z);
        unsafeAtomicAdd(dst + 3, val.w);
    }
}

// ---------------- out[b][j] = relu(max_n v[b,n,j]) ----------------
// thread per (b, j): 65536 threads
__global__ __launch_bounds__(256) void segmax_k(const float* __restrict__ v,
                                                float* __restrict__ out) {
    int t = blockIdx.x * 256 + threadIdx.x;
    int b = t >> 7;
    int j = t & 127;
    const float* base = v + (long long)b * NPB * DIM + j;
    float m = -INFINITY;
    #pragma unroll 4
    for (int n = 0; n < NPB; ++n) m = fmaxf(m, base[n * DIM]);
    out[t] = fmaxf(m, 0.0f);
}

extern "C" void kernel_launch(void* const* d_in, const int* in_sizes, int n_in,
                              void* d_out, int out_size, void* d_ws, size_t ws_size,
                              hipStream_t stream) {
    const int*   tokens = (const int*)d_in[0];
    const int*   parent = (const int*)d_in[1];
    const int*   depth  = (const int*)d_in[2];
    // d_in[3] = node2batch (unused: == n / 500 by construction)
    const float* emb    = (const float*)d_in[4];
    const float* Wc     = (const float*)d_in[5];
    const float* bc     = (const float*)d_in[6];
    float*       out    = (float*)d_out;

    // workspace layout
    float* E = (float*)d_ws;                         // VOCAB*DIM floats (25.6 MB)
    float* v = E + (long long)VOCAB * DIM;           // T*DIM floats (131 MB)
    int*   meta    = (int*)(v + (long long)T_NODES * DIM);
    int*   counts  = meta;                           // 64
    int*   offsets = meta + 64;                      // 64
    int*   cursor  = meta + 128;                     // 64
    int*   list    = meta + 192;                     // T ints

    zero_k<<<1, 64, 0, stream>>>(counts);
    gemm_E<<<VOCAB / 8, 256, 0, stream>>>(emb, Wc, bc, E);
    gather_init<<<T_NODES / 8, 256, 0, stream>>>(tokens, depth, E, v, counts);
    offsets_k<<<1, 64, 0, stream>>>(counts, offsets, cursor);
    scatter_k<<<(T_NODES + 255) / 256, 256, 0, stream>>>(depth, cursor, list);
    for (int d = MAXD; d >= 1; --d)
        level_k<<<512, 256, 0, stream>>>(d, offsets, counts, list, parent, v);
    segmax_k<<<(B_BATCH * DIM) / 256, 256, 0, stream>>>(v, out);
}

// Round 2
// 1179.896 us; speedup vs baseline: 1.8734x; 1.8734x over previous
//
#include <hip/hip_runtime.h>
#include <hip/hip_bf16.h>

#define T_NODES 256000
#define B_BATCH 512
#define NPB     500
#define DIM     128
#define VOCAB   50000
#define MAXD    40

// ---------------- zero small meta ----------------
__global__ void zero_k(int* counts) {
    if (threadIdx.x <= MAXD) counts[threadIdx.x] = 0;
}

// ---------------- E = emb @ Wc + bc (f32, LDS-tiled) ----------------
// grid: VOCAB/8 blocks, 256 threads. Each block: 8 vocab rows.
__global__ __launch_bounds__(256) void gemm_E(const float* __restrict__ emb,
                                              const float* __restrict__ Wc,
                                              const float* __restrict__ bc,
                                              float* __restrict__ E) {
    __shared__ float sW[DIM * DIM];     // 64 KB
    __shared__ float sE[8][DIM];        // 4 KB
    // load Wc (16384 floats = 4096 float4)
    for (int i = threadIdx.x; i < DIM * DIM / 4; i += 256)
        ((float4*)sW)[i] = ((const float4*)Wc)[i];
    int rowBase = blockIdx.x * 8;
    // load 8 emb rows (1024 floats = 256 float4)
    ((float4*)&sE[0][0])[threadIdx.x] = ((const float4*)(emb + (long long)rowBase * DIM))[threadIdx.x];
    __syncthreads();

    int r  = threadIdx.x >> 5;          // 0..7
    int j4 = (threadIdx.x & 31) * 4;    // 0..124
    float4 acc = make_float4(0.f, 0.f, 0.f, 0.f);
    #pragma unroll 8
    for (int k = 0; k < DIM; ++k) {
        float e = sE[r][k];
        float4 w = *(float4*)&sW[k * DIM + j4];
        acc.x += e * w.x; acc.y += e * w.y; acc.z += e * w.z; acc.w += e * w.w;
    }
    float4 b4 = *(const float4*)&bc[j4];
    acc.x += b4.x; acc.y += b4.y; acc.z += b4.z; acc.w += b4.w;
    *(float4*)&E[(long long)(rowBase + r) * DIM + j4] = acc;
}

// ---------------- v[n] = E[tokens[n]] ; histogram depths ----------------
// grid: T/8 blocks, 256 threads (8 nodes x 32 j-quads per block)
__global__ __launch_bounds__(256) void gather_init(const int* __restrict__ tokens,
                                                   const int* __restrict__ depth,
                                                   const float* __restrict__ E,
                                                   float* __restrict__ v,
                                                   int* __restrict__ counts) {
    __shared__ int hist[MAXD + 1];
    if (threadIdx.x <= MAXD) hist[threadIdx.x] = 0;
    __syncthreads();

    int n  = blockIdx.x * 8 + (threadIdx.x >> 5);
    int j4 = (threadIdx.x & 31) * 4;
    int tok = tokens[n];
    float4 val = *(const float4*)&E[(long long)tok * DIM + j4];
    *(float4*)&v[(long long)n * DIM + j4] = val;
    if (j4 == 0) atomicAdd(&hist[depth[n]], 1);

    __syncthreads();
    if (threadIdx.x <= MAXD) {
        int h = hist[threadIdx.x];
        if (h > 0) atomicAdd(&counts[threadIdx.x], h);
    }
}

// ---------------- prefix over 41 counts ----------------
__global__ void offsets_k(const int* __restrict__ counts, int* __restrict__ offsets,
                          int* __restrict__ cursor) {
    if (threadIdx.x == 0) {
        int acc = 0;
        for (int d = 0; d <= MAXD; ++d) {
            offsets[d] = acc; cursor[d] = acc; acc += counts[d];
        }
    }
}

// ---------------- scatter node ids into depth buckets ----------------
// Two-level aggregation: LDS histogram -> one global atomic per (block,depth)
// -> conflict-free list writes. Kills the 41-address global contention that
// made the naive version 1049 us.
__global__ __launch_bounds__(256) void scatter_k(const int* __restrict__ depth,
                                                 int* __restrict__ cursor,
                                                 int* __restrict__ list) {
    __shared__ int hist[MAXD + 1];
    __shared__ int base[MAXD + 1];
    int tid = threadIdx.x;
    if (tid <= MAXD) hist[tid] = 0;
    __syncthreads();

    int n = blockIdx.x * 256 + tid;
    int d = 0, lpos = 0;
    bool valid = (n < T_NODES);
    if (valid) {
        d = depth[n];
        lpos = atomicAdd(&hist[d], 1);   // LDS atomic — fast
    }
    __syncthreads();
    if (tid <= MAXD) {
        int h = hist[tid];
        base[tid] = (h > 0) ? atomicAdd(&cursor[tid], h) : 0;  // 1 global atomic per depth per block
    }
    __syncthreads();
    if (valid) list[base[d] + lpos] = n;
}

// ---------------- one propagation level: v[parent] += v[node] ----------------
// fixed grid (512x256), grid-stride over count[d]*32 (node, j4) tasks
__global__ __launch_bounds__(256) void level_k(int d,
                                               const int* __restrict__ offsets,
                                               const int* __restrict__ counts,
                                               const int* __restrict__ list,
                                               const int* __restrict__ parent,
                                               float* __restrict__ v) {
    int c   = counts[d];
    int off = offsets[d];
    int tasks = c * 32;
    for (int t = blockIdx.x * 256 + threadIdx.x; t < tasks; t += gridDim.x * 256) {
        int idx = t >> 5;
        int j4  = (t & 31) * 4;
        int n = list[off + idx];
        int p = parent[n];
        float4 val = *(const float4*)&v[(long long)n * DIM + j4];
        float* dst = &v[(long long)p * DIM + j4];
        unsafeAtomicAdd(dst + 0, val.x);
        unsafeAtomicAdd(dst + 1, val.y);
        unsafeAtomicAdd(dst + 2, val.z);
        unsafeAtomicAdd(dst + 3, val.w);
    }
}

// ---------------- out[b][j] = relu(max_n v[b,n,j]) ----------------
// thread per (b, j): 65536 threads
__global__ __launch_bounds__(256) void segmax_k(const float* __restrict__ v,
                                                float* __restrict__ out) {
    int t = blockIdx.x * 256 + threadIdx.x;
    int b = t >> 7;
    int j = t & 127;
    const float* base = v + (long long)b * NPB * DIM + j;
    float m = -INFINITY;
    #pragma unroll 4
    for (int n = 0; n < NPB; ++n) m = fmaxf(m, base[n * DIM]);
    out[t] = fmaxf(m, 0.0f);
}

extern "C" void kernel_launch(void* const* d_in, const int* in_sizes, int n_in,
                              void* d_out, int out_size, void* d_ws, size_t ws_size,
                              hipStream_t stream) {
    const int*   tokens = (const int*)d_in[0];
    const int*   parent = (const int*)d_in[1];
    const int*   depth  = (const int*)d_in[2];
    // d_in[3] = node2batch (unused: == n / 500 by construction)
    const float* emb    = (const float*)d_in[4];
    const float* Wc     = (const float*)d_in[5];
    const float* bc     = (const float*)d_in[6];
    float*       out    = (float*)d_out;

    // workspace layout
    float* E = (float*)d_ws;                         // VOCAB*DIM floats (25.6 MB)
    float* v = E + (long long)VOCAB * DIM;           // T*DIM floats (131 MB)
    int*   meta    = (int*)(v + (long long)T_NODES * DIM);
    int*   counts  = meta;                           // 64
    int*   offsets = meta + 64;                      // 64
    int*   cursor  = meta + 128;                     // 64
    int*   list    = meta + 192;                     // T ints

    zero_k<<<1, 64, 0, stream>>>(counts);
    gemm_E<<<VOCAB / 8, 256, 0, stream>>>(emb, Wc, bc, E);
    gather_init<<<T_NODES / 8, 256, 0, stream>>>(tokens, depth, E, v, counts);
    offsets_k<<<1, 64, 0, stream>>>(counts, offsets, cursor);
    scatter_k<<<(T_NODES + 255) / 256, 256, 0, stream>>>(depth, cursor, list);
    for (int d = MAXD; d >= 1; --d)
        level_k<<<512, 256, 0, stream>>>(d, offsets, counts, list, parent, v);
    segmax_k<<<(B_BATCH * DIM) / 256, 256, 0, stream>>>(v, out);
}

// Round 3
// 658.853 us; speedup vs baseline: 3.3549x; 1.7908x over previous
//
#include <hip/hip_runtime.h>
#include <hip/hip_bf16.h>

#define T_NODES 256000
#define B_BATCH 512
#define NPB     500
#define DIM     128
#define VOCAB   50000
#define MAXD    40

// ---------------- E = emb @ Wc + bc (f32, LDS-tiled) ----------------
__global__ __launch_bounds__(256) void gemm_E(const float* __restrict__ emb,
                                              const float* __restrict__ Wc,
                                              const float* __restrict__ bc,
                                              float* __restrict__ E) {
    __shared__ float sW[DIM * DIM];     // 64 KB
    __shared__ float sE[8][DIM];        // 4 KB
    for (int i = threadIdx.x; i < DIM * DIM / 4; i += 256)
        ((float4*)sW)[i] = ((const float4*)Wc)[i];
    int rowBase = blockIdx.x * 8;
    ((float4*)&sE[0][0])[threadIdx.x] = ((const float4*)(emb + (long long)rowBase * DIM))[threadIdx.x];
    __syncthreads();

    int r  = threadIdx.x >> 5;
    int j4 = (threadIdx.x & 31) * 4;
    float4 acc = make_float4(0.f, 0.f, 0.f, 0.f);
    #pragma unroll 8
    for (int k = 0; k < DIM; ++k) {
        float e = sE[r][k];
        float4 w = *(float4*)&sW[k * DIM + j4];
        acc.x += e * w.x; acc.y += e * w.y; acc.z += e * w.z; acc.w += e * w.w;
    }
    float4 b4 = *(const float4*)&bc[j4];
    acc.x += b4.x; acc.y += b4.y; acc.z += b4.z; acc.w += b4.w;
    *(float4*)&E[(long long)(rowBase + r) * DIM + j4] = acc;
}

// ---------------- fused per-tree kernel ----------------
// One block per tree (512 blocks x 256 threads). Does: local depth bucketing,
// gather v[n]=E[tok[n]], 40-level in-block propagation (global f32 atomics on
// this tree's L2-resident 256KB slab, __syncthreads between levels), and a
// fused segment-max (node value is final exactly when its level processes it).
__global__ __launch_bounds__(256) void tree_fused(const int* __restrict__ tokens,
                                                  const int* __restrict__ parent,
                                                  const int* __restrict__ depth,
                                                  const float* __restrict__ E,
                                                  float* __restrict__ v,
                                                  float* __restrict__ out) {
    const int b   = blockIdx.x;
    const int tid = threadIdx.x;
    const long long nbase = (long long)b * NPB;
    float* vb = v + nbase * DIM;          // this tree's 256 KB slab

    __shared__ int hist[MAXD + 1];
    __shared__ int off [MAXD + 1];
    __shared__ int cur [MAXD + 1];
    __shared__ unsigned short bucket[NPB];   // node ids sorted by depth (depths 1..40)
    __shared__ unsigned short par[NPB];      // local parent id
    __shared__ unsigned short dep[NPB];
    __shared__ int   tokL[NPB];
    __shared__ float smax[8][DIM];           // per-wave-group running max

    if (tid <= MAXD) hist[tid] = 0;
    __syncthreads();

    // pass 1: stage meta into LDS + local histogram (LDS atomics only)
    for (int n = tid; n < NPB; n += 256) {
        int d = depth[nbase + n];
        dep[n]  = (unsigned short)d;
        par[n]  = (unsigned short)(n == 0 ? 0 : (int)(parent[nbase + n] - nbase));
        tokL[n] = tokens[nbase + n];
        if (n > 0) atomicAdd(&hist[d], 1);
    }
    __syncthreads();

    // prefix (41 entries — single thread is fine)
    if (tid == 0) {
        int acc = 0;
        for (int d = 1; d <= MAXD; ++d) { off[d] = acc; cur[d] = acc; acc += hist[d]; }
    }
    __syncthreads();

    // pass 2: scatter into local buckets (LDS atomics)
    for (int n = 1 + tid; n < NPB; n += 256) {
        int pos = atomicAdd(&cur[dep[n]], 1);
        bucket[pos] = (unsigned short)n;
    }

    // gather: v[n] = E[tok[n]]  (4-way batched for MLP; overlaps with pass 2)
    {
        const int TASKS = NPB * 32;          // (node, j4) tasks
        for (int t0 = tid; t0 < TASKS; t0 += 1024) {
            float4 a[4];
            int    dst[4];
            int    k = 0;
            #pragma unroll
            for (int u = 0; u < 4; ++u) {
                int t = t0 + u * 256;
                if (t < TASKS) {
                    int n  = t >> 5;
                    int j4 = (t & 31) << 2;
                    a[k]   = *(const float4*)&E[(long long)tokL[n] * DIM + j4];
                    dst[k] = n * DIM + j4;
                    ++k;
                }
            }
            for (int u = 0; u < k; ++u)
                *(float4*)&vb[dst[u]] = a[u];
        }
    }
    __syncthreads();

    // level loop, deepest first; fused running max (value is final when read)
    const int j4 = (tid & 31) << 2;          // constant per thread (256 % 32 == 0)
    float m0 = -INFINITY, m1 = -INFINITY, m2 = -INFINITY, m3 = -INFINITY;
    for (int d = MAXD; d >= 1; --d) {
        int c = hist[d];
        int o = off[d];
        for (int i = tid; i < c * 32; i += 256) {
            int n = bucket[o + (i >> 5)];
            const float* src = &vb[n * DIM + j4];
            // agent-scope loads: guarantee we see prior-level L2 atomics (bypass L1)
            float x0 = __hip_atomic_load(src + 0, __ATOMIC_RELAXED, __HIP_MEMORY_SCOPE_AGENT);
            float x1 = __hip_atomic_load(src + 1, __ATOMIC_RELAXED, __HIP_MEMORY_SCOPE_AGENT);
            float x2 = __hip_atomic_load(src + 2, __ATOMIC_RELAXED, __HIP_MEMORY_SCOPE_AGENT);
            float x3 = __hip_atomic_load(src + 3, __ATOMIC_RELAXED, __HIP_MEMORY_SCOPE_AGENT);
            float* dstp = &vb[par[n] * DIM + j4];
            unsafeAtomicAdd(dstp + 0, x0);
            unsafeAtomicAdd(dstp + 1, x1);
            unsafeAtomicAdd(dstp + 2, x2);
            unsafeAtomicAdd(dstp + 3, x3);
            m0 = fmaxf(m0, x0); m1 = fmaxf(m1, x1);
            m2 = fmaxf(m2, x2); m3 = fmaxf(m3, x3);
        }
        __syncthreads();
    }

    // reduce the 8 thread-groups' maxes, fold in the root row, ReLU, store
    smax[tid >> 5][j4 + 0] = m0;
    smax[tid >> 5][j4 + 1] = m1;
    smax[tid >> 5][j4 + 2] = m2;
    smax[tid >> 5][j4 + 3] = m3;
    __syncthreads();
    if (tid < DIM) {
        float m = smax[0][tid];
        #pragma unroll
        for (int g = 1; g < 8; ++g) m = fmaxf(m, smax[g][tid]);
        float rv = __hip_atomic_load(&vb[tid], __ATOMIC_RELAXED, __HIP_MEMORY_SCOPE_AGENT);
        m = fmaxf(m, rv);
        out[b * DIM + tid] = fmaxf(m, 0.0f);
    }
}

extern "C" void kernel_launch(void* const* d_in, const int* in_sizes, int n_in,
                              void* d_out, int out_size, void* d_ws, size_t ws_size,
                              hipStream_t stream) {
    const int*   tokens = (const int*)d_in[0];
    const int*   parent = (const int*)d_in[1];
    const int*   depth  = (const int*)d_in[2];
    // d_in[3] = node2batch (unused: node2batch[n] == n / 500 by construction)
    const float* emb    = (const float*)d_in[4];
    const float* Wc     = (const float*)d_in[5];
    const float* bc     = (const float*)d_in[6];
    float*       out    = (float*)d_out;

    float* E = (float*)d_ws;                       // VOCAB*DIM floats (25.6 MB)
    float* v = E + (long long)VOCAB * DIM;         // T*DIM floats (131 MB)

    gemm_E<<<VOCAB / 8, 256, 0, stream>>>(emb, Wc, bc, E);
    tree_fused<<<B_BATCH, 256, 0, stream>>>(tokens, parent, depth, E, v, out);
}

// Round 4
// 321.220 us; speedup vs baseline: 6.8813x; 2.0511x over previous
//
#include <hip/hip_runtime.h>

#define B_BATCH 512
#define NPB     500
#define DIM     128
#define VOCAB   50000
#define MAXD    40
#define SLICE   16
#define NSLICE  (DIM / SLICE)   // 8

// ---------------- E = emb @ Wc + bc ----------------
// 32 vocab rows per block; micro-tile 4 rows x 4 cols per thread.
// sW reads: b128, lanes 0-31 contiguous + upper-half broadcast (conflict-free).
// sE reads: scalar broadcasts (2 distinct addrs/wave, same bank -> 2-way = free).
__global__ __launch_bounds__(256) void gemm_E(const float* __restrict__ emb,
                                              const float* __restrict__ Wc,
                                              const float* __restrict__ bc,
                                              float* __restrict__ E) {
    __shared__ float sW[DIM * DIM];   // 64 KB
    __shared__ float sE[32 * DIM];    // 16 KB
    const int tid = threadIdx.x;

    for (int i = tid; i < DIM * DIM / 4; i += 256)
        ((float4*)sW)[i] = ((const float4*)Wc)[i];

    const int rowBase = blockIdx.x * 32;
    for (int f = tid; f < 32 * DIM / 4; f += 256) {
        int r  = f >> 5;            // 0..31
        int k4 = (f & 31) * 4;
        float4 v = make_float4(0.f, 0.f, 0.f, 0.f);
        if (rowBase + r < VOCAB)
            v = *(const float4*)&emb[(long long)(rowBase + r) * DIM + k4];
        *(float4*)&sE[r * DIM + k4] = v;
    }
    __syncthreads();

    const int rg = tid >> 5;        // 0..7 -> rows r0..r0+3
    const int r0 = rg * 4;
    const int j4 = (tid & 31) * 4;

    float4 a0 = make_float4(0.f,0.f,0.f,0.f), a1 = a0, a2 = a0, a3 = a0;
    #pragma unroll 8
    for (int k = 0; k < DIM; ++k) {
        float4 w = *(float4*)&sW[k * DIM + j4];
        float e0 = sE[(r0 + 0) * DIM + k];
        float e1 = sE[(r0 + 1) * DIM + k];
        float e2 = sE[(r0 + 2) * DIM + k];
        float e3 = sE[(r0 + 3) * DIM + k];
        a0.x += e0*w.x; a0.y += e0*w.y; a0.z += e0*w.z; a0.w += e0*w.w;
        a1.x += e1*w.x; a1.y += e1*w.y; a1.z += e1*w.z; a1.w += e1*w.w;
        a2.x += e2*w.x; a2.y += e2*w.y; a2.z += e2*w.z; a2.w += e2*w.w;
        a3.x += e3*w.x; a3.y += e3*w.y; a3.z += e3*w.z; a3.w += e3*w.w;
    }
    float4 b4 = *(const float4*)&bc[j4];
    a0.x += b4.x; a0.y += b4.y; a0.z += b4.z; a0.w += b4.w;
    a1.x += b4.x; a1.y += b4.y; a1.z += b4.z; a1.w += b4.w;
    a2.x += b4.x; a2.y += b4.y; a2.z += b4.z; a2.w += b4.w;
    a3.x += b4.x; a3.y += b4.y; a3.z += b4.z; a3.w += b4.w;

    #pragma unroll
    for (int u = 0; u < 4; ++u) {
        int r = rowBase + r0 + u;
        if (r < VOCAB) {
            float4 a = (u == 0) ? a0 : (u == 1) ? a1 : (u == 2) ? a2 : a3;
            *(float4*)&E[(long long)r * DIM + j4] = a;
        }
    }
}

// ---------------- fused per-(tree, dim-slice) kernel ----------------
// grid = 512 trees x 8 slices. Entire propagation state (500 nodes x 16 dims)
// lives in LDS: gather E-slice -> 40-level bottom-up with ds_add_f32 atomics
// + __syncthreads -> fused running max -> 16 output floats. No global v.
__global__ __launch_bounds__(256) void tree_slice(const int* __restrict__ tokens,
                                                  const int* __restrict__ parent,
                                                  const int* __restrict__ depth,
                                                  const float* __restrict__ E,
                                                  float* __restrict__ out) {
    const int b   = blockIdx.x >> 3;    // tree
    const int s   = blockIdx.x & 7;     // dim-slice
    const int tid = threadIdx.x;
    const long long nbase = (long long)b * NPB;

    __shared__ float vL[NPB * SLICE];          // 32000 B
    __shared__ unsigned short bucket[NPB];     // 1000 B
    __shared__ unsigned short par[NPB];        // 1000 B
    __shared__ unsigned short dep[NPB];        // 1000 B
    __shared__ int tokL[NPB];                  // 2000 B
    __shared__ int hist[MAXD + 1];
    __shared__ int off [MAXD + 1];
    __shared__ int cur [MAXD + 1];
    __shared__ int sdmax;

    if (tid <= MAXD) hist[tid] = 0;
    if (tid == 0) sdmax = 0;
    __syncthreads();

    // pass 1: stage meta, histogram depths, track max depth (all LDS atomics)
    for (int n = tid; n < NPB; n += 256) {
        int d = depth[nbase + n];
        dep[n]  = (unsigned short)d;
        par[n]  = (unsigned short)(n == 0 ? 0 : (int)(parent[nbase + n] - nbase));
        tokL[n] = tokens[nbase + n];
        if (n > 0) { atomicAdd(&hist[d], 1); atomicMax(&sdmax, d); }
    }
    __syncthreads();

    if (tid == 0) {
        int acc = 0;
        for (int d = 1; d <= MAXD; ++d) { off[d] = acc; cur[d] = acc; acc += hist[d]; }
    }
    __syncthreads();

    // pass 2: bucket nodes by depth (LDS atomics) — overlaps with the gather
    for (int n = 1 + tid; n < NPB; n += 256)
        bucket[atomicAdd(&cur[dep[n]], 1)] = (unsigned short)n;

    // gather this slice of E[tok[n]] into LDS (float4 per thread)
    for (int t = tid; t < NPB * 4; t += 256) {
        int n = t >> 2;
        int q = (t & 3) * 4;
        float4 x = *(const float4*)&E[(long long)tokL[n] * DIM + s * SLICE + q];
        *(float4*)&vL[n * SLICE + q] = x;
    }
    __syncthreads();

    // level loop, deepest first; all adds are LDS ds_add_f32
    const int dmax = sdmax;
    const int j = tid & 15;                  // fixed per thread (256 % 16 == 0)
    float m = -INFINITY;
    for (int d = dmax; d >= 1; --d) {
        int c = hist[d];
        int o = off[d];
        for (int i = tid; i < c * 16; i += 256) {
            int n = bucket[o + (i >> 4)];
            float x = vL[n * SLICE + j];     // final: children were prior levels
            atomicAdd(&vL[par[n] * SLICE + j], x);
            m = fmaxf(m, x);
        }
        __syncthreads();
    }

    // reduce the 16 thread-groups' maxes; rows 1..16 of vL are dead now
    int g = tid >> 4;
    vL[(1 + g) * SLICE + j] = m;
    __syncthreads();
    if (tid < SLICE) {
        float mm = vL[SLICE + tid];
        #pragma unroll
        for (int g2 = 1; g2 < 16; ++g2) mm = fmaxf(mm, vL[(1 + g2) * SLICE + tid]);
        mm = fmaxf(mm, vL[tid]);             // root (node 0) value
        out[b * DIM + s * SLICE + tid] = fmaxf(mm, 0.0f);
    }
}

extern "C" void kernel_launch(void* const* d_in, const int* in_sizes, int n_in,
                              void* d_out, int out_size, void* d_ws, size_t ws_size,
                              hipStream_t stream) {
    const int*   tokens = (const int*)d_in[0];
    const int*   parent = (const int*)d_in[1];
    const int*   depth  = (const int*)d_in[2];
    // d_in[3] = node2batch (unused: node2batch[n] == n / 500 by construction)
    const float* emb    = (const float*)d_in[4];
    const float* Wc     = (const float*)d_in[5];
    const float* bc     = (const float*)d_in[6];
    float*       out    = (float*)d_out;

    float* E = (float*)d_ws;   // VOCAB*DIM floats (25.6 MB)

    gemm_E<<<(VOCAB + 31) / 32, 256, 0, stream>>>(emb, Wc, bc, E);
    tree_slice<<<B_BATCH * NSLICE, 256, 0, stream>>>(tokens, parent, depth, E, out);
}